// Round 1
// 8371.408 us; speedup vs baseline: 1.5593x; 1.5593x over previous
//
#include <hip/hip_runtime.h>
#include <hip/hip_fp16.h>

#define RES 512
#define NF 32

static __device__ __forceinline__ float h2f(float v) {
    return __half2float(__float2half(v));
}

// Constant-index component select — folds at compile time under full unroll,
// avoids taking the address of float4 locals (alloca/scratch risk).
#define GET(v, c) ((c) == 0 ? (v).x : ((c) == 1 ? (v).y : ((c) == 2 ? (v).z : (v).w)))

// One thread per point. Streaming restructure of the previous kernel:
// the gather is processed in 8 chunks of 4 features; each chunk's h / per-axis
// derivative values are consumed IMMEDIATELY into four persistent 32-wide
// accumulators:
//   y[j]  = sum_i h16[i]   * W1s[i][j]   (fp16-emulated, exact op order)
//   eA[j] = sum_i D_A[i]   * W1s[i][j]   (fp32, backward — reassociated from
//                                         the old g[i]=sum_j m_j W1s[i][j] form)
// so h[32], D0/D1/D2[96], g[32] never exist as whole arrays. Persistent live
// set drops from ~200+ floats (which spilled to scratch: 16 GB WRITE_SIZE)
// to 128 floats. Forward h and all fp16 MLP pre-activations keep numpy-exact
// semantics (contract off, identical op order/associativity/rounding) so every
// leaky-ReLU sign decision matches the reference bitwise. Backward (m, e, n)
// stays fp32 value-level.
__global__ __launch_bounds__(256) void stylesdf_fused(
    const float* __restrict__ x,
    const float* __restrict__ planes,
    const float* __restrict__ W1,
    const float* __restrict__ b1,
    const float* __restrict__ W2,
    const float* __restrict__ b2,
    float* __restrict__ out, int N)
{
#pragma clang fp contract(off)
    __shared__ __align__(16) float sW1[NF * NF];   // fp16-valued W1*s, row-major [i][j]
    __shared__ __align__(16) float sW2[NF * 4];    // fp16-valued W2*s
    __shared__ __align__(16) float sB1[NF];
    __shared__ __align__(16) float sB2[4];
    __shared__ __align__(16) float sW2c0[NF];

    const float S16 = h2f(0.17677669529663687f);  // fp16(1/sqrt(32))
    const float LREL = h2f(0.2f);                 // fp16(0.2) = 0.199951171875

    const int tid = threadIdx.x;
    for (int idx = tid; idx < NF * NF; idx += 256)
        sW1[idx] = h2f(h2f(W1[idx]) * S16);  // fp16 multiply semantics
    if (tid < NF * 4) sW2[tid] = h2f(h2f(W2[tid]) * S16);
    if (tid < NF) { sB1[tid] = h2f(b1[tid]); sW2c0[tid] = h2f(h2f(W2[tid * 4]) * S16); }
    if (tid < 4) sB2[tid] = h2f(b2[tid]);
    __syncthreads();

    const int p = blockIdx.x * 256 + tid;
    if (p >= N) return;

    // ---- per-axis interp coordinates (identical ops to previous kernel) ----
    float fr0, fr1, fr2;
    int ax0lo, ax0hi, ax1lo, ax1hi, ax2lo, ax2hi;
#define AXIS(c, FR, LO, HI)                                 \
    {                                                       \
        float xt = (x[3 * p + (c)] + 1.0f) * 0.5f;          \
        float pos = xt * 511.0f;                            \
        float pf = floorf(pos);                             \
        FR = pos - pf;                                      \
        int q = (int)pf;                                    \
        q = q < 0 ? 0 : (q > 511 ? 511 : q);                \
        LO = q;                                             \
        HI = (q + 1 > 511) ? 511 : q + 1;                   \
    }
    AXIS(0, fr0, ax0lo, ax0hi)
    AXIS(1, fr1, ax1lo, ax1hi)
    AXIS(2, fr2, ax2lo, ax2hi)
#undef AXIS

    // ---- 12 corner row pointers (each row = 32 floats = 8 float4, 128B aligned) ----
    const float* pl1 = planes + RES * RES * NF;
    const float* pl2 = planes + 2 * RES * RES * NF;
    const float4* P00 = (const float4*)(planes + ((ax0lo * RES + ax1lo) << 5));
    const float4* P01 = (const float4*)(planes + ((ax0lo * RES + ax1hi) << 5));
    const float4* P10 = (const float4*)(planes + ((ax0hi * RES + ax1lo) << 5));
    const float4* P11 = (const float4*)(planes + ((ax0hi * RES + ax1hi) << 5));
    const float4* Q00 = (const float4*)(pl1 + ((ax0lo * RES + ax2lo) << 5));
    const float4* Q01 = (const float4*)(pl1 + ((ax0lo * RES + ax2hi) << 5));
    const float4* Q10 = (const float4*)(pl1 + ((ax0hi * RES + ax2lo) << 5));
    const float4* Q11 = (const float4*)(pl1 + ((ax0hi * RES + ax2hi) << 5));
    const float4* R00 = (const float4*)(pl2 + ((ax1lo * RES + ax2lo) << 5));
    const float4* R01 = (const float4*)(pl2 + ((ax1lo * RES + ax2hi) << 5));
    const float4* R10 = (const float4*)(pl2 + ((ax1hi * RES + ax2lo) << 5));
    const float4* R11 = (const float4*)(pl2 + ((ax1hi * RES + ax2hi) << 5));

    // ---- persistent accumulators: the ONLY large live state (128 regs) ----
    float y[NF], e0[NF], e1[NF], e2[NF];
#pragma unroll
    for (int j = 0; j < NF; ++j) { y[j] = 0.f; e0[j] = 0.f; e1[j] = 0.f; e2[j] = 0.f; }

    float4* ho = (float4*)(out + (size_t)N + (size_t)p * NF);

    const float ifa01 = 1.0f - fr0, ifb01 = 1.0f - fr1;  // plane0 axes (0,1)
    const float ifa02 = 1.0f - fr0, ifb02 = 1.0f - fr2;  // plane1 axes (0,2)
    const float ifa12 = 1.0f - fr1, ifb12 = 1.0f - fr2;  // plane2 axes (1,2)

#pragma unroll
    for (int q = 0; q < 8; ++q) {
        // 12 texel-chunk loads (issued up front so they overlap compute)
        const float4 vA00 = P00[q], vA01 = P01[q], vA10 = P10[q], vA11 = P11[q];
        const float4 vB00 = Q00[q], vB01 = Q01[q], vB10 = Q10[q], vB11 = Q11[q];
        const float4 vC00 = R00[q], vC01 = R01[q], vC10 = R10[q], vC11 = R11[q];

        float hc[4], d0c[4], d1c[4], d2c[4];
#pragma unroll
        for (int c = 0; c < 4; ++c) {
            // plane 0, axes (0,1): bitwise-exact h order: h = (h + t4) + t8
            {
                const float a00 = GET(vA00, c), a01 = GET(vA01, c);
                const float a10 = GET(vA10, c), a11 = GET(vA11, c);
                const float t4 = (a00 * ifb01 + a01 * fr1) * ifa01;
                const float t8 = (a10 * ifb01 + a11 * fr1) * fr0;
                hc[c] = t4 + t8;  // h starts at 0: (0+t4)+t8 == t4+t8 (value-exact)
                d0c[c] = (a10 - a00) * ifb01 + (a11 - a01) * fr1;
                d1c[c] = (a01 - a00) * ifa01 + (a11 - a10) * fr0;
            }
            // plane 1, axes (0,2)
            {
                const float a00 = GET(vB00, c), a01 = GET(vB01, c);
                const float a10 = GET(vB10, c), a11 = GET(vB11, c);
                const float t4 = (a00 * ifb02 + a01 * fr2) * ifa02;
                const float t8 = (a10 * ifb02 + a11 * fr2) * fr0;
                hc[c] = (hc[c] + t4) + t8;
                d0c[c] += (a10 - a00) * ifb02 + (a11 - a01) * fr2;
                d2c[c] = (a01 - a00) * ifa02 + (a11 - a10) * fr0;
            }
            // plane 2, axes (1,2)
            {
                const float a00 = GET(vC00, c), a01 = GET(vC01, c);
                const float a10 = GET(vC10, c), a11 = GET(vC11, c);
                const float t4 = (a00 * ifb12 + a01 * fr2) * ifa12;
                const float t8 = (a10 * ifb12 + a11 * fr2) * fr1;
                hc[c] = (hc[c] + t4) + t8;
                d1c[c] += (a10 - a00) * ifb12 + (a11 - a01) * fr2;
                d2c[c] += (a01 - a00) * ifa12 + (a11 - a10) * fr1;
            }
        }

        // store fp32 h chunk (pre-rounding, bitwise-matching np order)
        ho[q] = make_float4(hc[0], hc[1], hc[2], hc[3]);

        // rank-4 update of y (fp16-exact order: i ascending, round mul then
        // round add, contract off) and of e0/e1/e2 (fp32 fmaf, shared W1 row)
#pragma unroll
        for (int c = 0; c < 4; ++c) {
            const int i = 4 * q + c;
            const float hi = h2f(hc[c]);  // h16, fp16-valued
            const float dA = d0c[c], dB = d1c[c], dC = d2c[c];
            const float4* row = (const float4*)(sW1 + i * NF);
#pragma unroll
            for (int jq = 0; jq < 8; ++jq) {
                const float4 w = row[jq];
                y[4 * jq + 0] = y[4 * jq + 0] + hi * w.x;
                y[4 * jq + 1] = y[4 * jq + 1] + hi * w.y;
                y[4 * jq + 2] = y[4 * jq + 2] + hi * w.z;
                y[4 * jq + 3] = y[4 * jq + 3] + hi * w.w;
                e0[4 * jq + 0] = fmaf(dA, w.x, e0[4 * jq + 0]);
                e0[4 * jq + 1] = fmaf(dA, w.y, e0[4 * jq + 1]);
                e0[4 * jq + 2] = fmaf(dA, w.z, e0[4 * jq + 2]);
                e0[4 * jq + 3] = fmaf(dA, w.w, e0[4 * jq + 3]);
                e1[4 * jq + 0] = fmaf(dB, w.x, e1[4 * jq + 0]);
                e1[4 * jq + 1] = fmaf(dB, w.y, e1[4 * jq + 1]);
                e1[4 * jq + 2] = fmaf(dB, w.z, e1[4 * jq + 2]);
                e1[4 * jq + 3] = fmaf(dB, w.w, e1[4 * jq + 3]);
                e2[4 * jq + 0] = fmaf(dC, w.x, e2[4 * jq + 0]);
                e2[4 * jq + 1] = fmaf(dC, w.y, e2[4 * jq + 1]);
                e2[4 * jq + 2] = fmaf(dC, w.z, e2[4 * jq + 2]);
                e2[4 * jq + 3] = fmaf(dC, w.w, e2[4 * jq + 3]);
            }
        }
    }

    // ---- per-j: fp16 round, bias, leaky, layer-2 acc, m_j, nabla acc ----
    float o0 = 0.f, o1 = 0.f, o2 = 0.f, o3 = 0.f;
    float n0 = 0.f, n1 = 0.f, n2 = 0.f;
#pragma unroll
    for (int j = 0; j < NF; ++j) {
        const float yd = h2f(y[j]);            // fp16 dot result
        const float y16 = h2f(yd + sB1[j]);    // fp16 bias add
        const bool nn = y16 >= 0.0f;
        const float zj = nn ? y16 : h2f(LREL * y16);  // fp16 leaky value
        const float4 w2 = ((const float4*)sW2)[j];
        o0 = o0 + zj * w2.x;  // sequential fp32 accumulation over j (exact order)
        o1 = o1 + zj * w2.y;
        o2 = o2 + zj * w2.z;
        o3 = o3 + zj * w2.w;
        const float mj = (nn ? 1.0f : LREL) * sW2c0[j];
        n0 = fmaf(mj, e0[j], n0);  // n_axis = sum_j m_j * (D_axis @ W1s)[j]
        n1 = fmaf(mj, e1[j], n1);
        n2 = fmaf(mj, e2[j], n2);
    }
    // fp16 rounding of layer-2 output + bias (sdf/rgb pre-activations)
    o0 = h2f(h2f(o0) + sB2[0]);
    o1 = h2f(h2f(o1) + sB2[1]);
    o2 = h2f(h2f(o2) + sB2[2]);
    o3 = h2f(h2f(o3) + sB2[3]);

    n0 *= 511.0f; n1 *= 511.0f; n2 *= 511.0f;

    const float r0 = (tanhf(o1) + 1.0f) * 0.5f;
    const float r1 = (tanhf(o2) + 1.0f) * 0.5f;
    const float r2 = (tanhf(o3) + 1.0f) * 0.5f;

    // ---- stores ----
    out[p] = o0;  // sdf
    {
        const size_t nb = (size_t)N * 33 + (size_t)p * 3;
        out[nb + 0] = n0; out[nb + 1] = n1; out[nb + 2] = n2;
        const size_t rb = (size_t)N * 36 + (size_t)p * 3;
        out[rb + 0] = r0; out[rb + 1] = r1; out[rb + 2] = r2;
    }
}

extern "C" void kernel_launch(void* const* d_in, const int* in_sizes, int n_in,
                              void* d_out, int out_size, void* d_ws, size_t ws_size,
                              hipStream_t stream) {
    const float* x      = (const float*)d_in[0];
    const float* planes = (const float*)d_in[1];
    const float* W1     = (const float*)d_in[2];
    const float* b1     = (const float*)d_in[3];
    const float* W2     = (const float*)d_in[4];
    const float* b2     = (const float*)d_in[5];
    float* out = (float*)d_out;
    const int N = in_sizes[0] / 3;
    const int blocks = (N + 255) / 256;
    stylesdf_fused<<<blocks, 256, 0, stream>>>(x, planes, W1, b1, W2, b2, out, N);
}